// Round 7
// baseline (172.892 us; speedup 1.0000x reference)
//
#include <hip/hip_runtime.h>
#include <math.h>

// Sizes (fixed by the reference)
#define Zc   4
#define Nc   128
#define EMBc 16
#define L0c  32
#define MLPHc 64
#define GEOc 64
#define NBc  32
#define NHc  128
#define Cc   128   // MLPH + GEO
#define SLc  64    // split-K slices in gemm3

typedef float  f32x4  __attribute__((ext_vector_type(4)));
typedef short  bf16x8 __attribute__((ext_vector_type(8)));

union FragU {
    bf16x8 v;
    unsigned short u[8];
    uint2 q2[2];
};

// accurate softplus-shifted (fp32 chain, used in epi/x1f)
__device__ __forceinline__ float sp5(float x){
    float y = 5.0f * x;
    float t = fabsf(y);
    return (fmaxf(y, 0.0f) + log1pf(__expf(-t))) * 0.2f;
}
// post-accumulator activation for MFMA path: input y = 5*preact (5 folded
// into packed weights).  ssp(y/5) = 0.2*(max(y,0)+log(1+exp(-|y|))) - log2/5
__device__ __forceinline__ float ssp5_post(float y){
    float e = __expf(-fabsf(y));
    float u = fmaxf(y, 0.0f) + __logf(1.0f + e);
    return fmaf(0.2f, u, -0.13862943611198906f);
}

// single-instruction f32->bf16 (RNE) via v_cvt_pk; low half = src0
__device__ __forceinline__ unsigned int cvtpk_bf16(float a, float b){
    unsigned int r;
    asm("v_cvt_pk_bf16_f32 %0, %1, %2" : "=v"(r) : "v"(a), "v"(b));
    return r;
}
__device__ __forceinline__ unsigned short f2bf(float f){   // packw only
    unsigned int u = __float_as_uint(f);
    unsigned int r = (u + 0x7FFFu + ((u >> 16) & 1u)) >> 16;
    return (unsigned short)r;
}

// shared k-map for MFMA fragments (A-gen and B-pack must agree)
__device__ __forceinline__ int kmap(int l, int e){
    return 4*((l >> 4) & 3) + (e & 3) + 16*(e >> 2);
}

// ---------------------------------------------------------------------------
// Pre-pack radial-MLP weights into per-lane MFMA B-fragment order (bf16),
// folding 5/sqrt(fan_in) (the softplus 5x folded in).  grid = (80,3), 256 thr.
__global__ __launch_bounds__(256) void k_packw(
    const float* __restrict__ w00, const float* __restrict__ w10,
    const float* __restrict__ w01, const float* __restrict__ w11,
    const float* __restrict__ w02, const float* __restrict__ w12,
    unsigned short* __restrict__ packs)
{
    int layer = blockIdx.y;
    const float* w0s = (layer == 0) ? w00 : (layer == 1) ? w01 : w02;
    const float* w1s = (layer == 0) ? w10 : (layer == 1) ? w11 : w12;
    unsigned short* p0 = packs + layer*4096;
    unsigned short* p1 = packs + 12288 + layer*16384;
    int idx = blockIdx.x*256 + threadIdx.x;
    if (idx < 4096){
        int t8 = idx >> 9, l = (idx >> 3) & 63, e = idx & 7;
        int k = kmap(l, e);
        int n = (t8 << 4) + (l & 15);
        p0[idx] = f2bf(w0s[k*NHc + n] * 0.8838834764831844f);    // 5/sqrt(32)
    } else {
        int j = idx - 4096;
        int fid = j >> 9, l = (j >> 3) & 63, e = j & 7;
        int kk = fid >> 3, t8 = fid & 7;
        int k = 32*kk + kmap(l, e);
        int n = 16*t8 + (l & 15);
        p1[j] = f2bf(w1s[k*NHc + n] * 0.4419417382415922f);      // 5/sqrt(128)
    }
}

// ---------------------------------------------------------------------------
// ResnetPointnet per atom + embedding lookup (f0 pre-scaled for gmat).
__global__ __launch_bounds__(64) void k_pointnet(
    const float* __restrict__ geom, const float* __restrict__ mask,
    const float* __restrict__ pw0, const float* __restrict__ pb0,
    const float* __restrict__ w1a, const float* __restrict__ b1a,
    const float* __restrict__ w1b, const float* __restrict__ b1b,
    const float* __restrict__ w2a, const float* __restrict__ b2a,
    const float* __restrict__ w2b, const float* __restrict__ b2b,
    const int*   __restrict__ features, const float* __restrict__ emb,
    float* __restrict__ geo_pn, float* __restrict__ f0)
{
    int zn = blockIdx.x;
    int c  = threadIdx.x;            // 0..63
    __shared__ float cur[GEOc];
    __shared__ float tmp[GEOc];
    float gx = geom[zn*3+0], gy = geom[zn*3+1], gz = geom[zn*3+2];
    float v = fmaf(gx, pw0[0*GEOc+c], fmaf(gy, pw0[1*GEOc+c], fmaf(gz, pw0[2*GEOc+c], pb0[c])));
    const float* WA[2] = {w1a, w2a}; const float* BA[2] = {b1a, b2a};
    const float* WB[2] = {w1b, w2b}; const float* BB[2] = {b1b, b2b};
    #pragma unroll
    for (int blk = 0; blk < 2; blk++){
        cur[c] = v;
        __syncthreads();
        float s = BA[blk][c];
        for (int k = 0; k < GEOc; k++) s = fmaf(fmaxf(cur[k], 0.0f), WA[blk][k*GEOc+c], s);
        tmp[c] = s;
        __syncthreads();
        float s2 = BB[blk][c];
        for (int k = 0; k < GEOc; k++) s2 = fmaf(fmaxf(tmp[k], 0.0f), WB[blk][k*GEOc+c], s2);
        v = v + s2;
        __syncthreads();
    }
    geo_pn[zn*GEOc + c] = v * mask[zn];
    if (c < EMBc){
        int fi = features[zn];
        // one mask (einsum's), Y0/128 scale pre-folded for gmat
        f0[zn*EMBc + c] = emb[fi*EMBc + c] * mask[zn] * 0.0022038655607334227f;
    }
}

// ---------------------------------------------------------------------------
// epilogue reducer: fprep[zb,j] = sp5(sum_sl part)*mask^2*Y0/128
template<int DIN>
__global__ __launch_bounds__(256) void k_epi(
    const float* __restrict__ part, const float* __restrict__ mask,
    float* __restrict__ fprep)
{
    int idx = blockIdx.x*256 + threadIdx.x;
    if (idx >= Zc*Nc*DIN) return;
    int zn = idx / DIN;
    float s = 0.0f;
    #pragma unroll
    for (int sl = 0; sl < SLc; sl++) s += part[(size_t)sl*(Zc*Nc*DIN) + idx];
    float m = mask[zn];
    fprep[idx] = sp5(s) * m * m * 0.0022038655607334227f;
}

// ---------------------------------------------------------------------------
// g_t[z][i][b*NH+m] = sum_j w2[m*DOUT+i, j] * fprep[zb,j]  (bf16, transposed)
// grid = (Z*N/8, NH*DOUT/256), 256 threads; thread owns 1 (m,i) x 8 zb-rows.
template<int DIN, int DOUT>
__global__ __launch_bounds__(256) void k_gmat(
    const float* __restrict__ f, const float* __restrict__ w2,
    unsigned short* __restrict__ gt)
{
    __shared__ float fsh[8][DIN];
    int t   = threadIdx.x;
    int zb0 = blockIdx.x * 8;
    if (t < 8*DIN){
        int r = t / DIN, j = t % DIN;
        fsh[r][j] = f[(zb0 + r)*DIN + j];
    }
    __syncthreads();
    int mi = blockIdx.y * 256 + t;      // = i*NH + m
    int m_ = mi & (NHc-1);
    int i_ = mi >> 7;
    const float* wrow = w2 + (size_t)(m_*DOUT + i_) * DIN;
    float s[8];
    #pragma unroll
    for (int r = 0; r < 8; r++) s[r] = 0.0f;
    #pragma unroll
    for (int j4 = 0; j4 < DIN/4; j4++){
        float4 w = *reinterpret_cast<const float4*>(&wrow[j4*4]);
        #pragma unroll
        for (int q = 0; q < 4; q++){
            float wv = reinterpret_cast<const float*>(&w)[q];
            int j = j4*4 + q;
            #pragma unroll
            for (int r = 0; r < 8; r++)
                s[r] = fmaf(fsh[r][j], wv, s[r]);
        }
    }
    int z = zb0 >> 7;
    #pragma unroll
    for (int r = 0; r < 8; r++){
        int b = (zb0 + r) & (Nc-1);
        gt[((size_t)z*DOUT + i_)*(Nc*NHc) + b*NHc + m_] = (unsigned short)cvtpk_bf16(s[r], s[r]);
    }
}

// ---------------------------------------------------------------------------
// MFMA pair-MLP for ALL 3 layers: basis(32)->ssp(128)->ssp(128)->h2 (bf16).
// grid = (1024, 3); block = 64 pairs (fixed z,a; b0..b0+63), 4 waves.
__global__ __launch_bounds__(256) void k_pairmlp(
    const float* __restrict__ geom,
    const unsigned short* __restrict__ packs,
    unsigned short* __restrict__ h2all)
{
    __shared__ unsigned short h1s[64*128];   // 16 KB, XOR-swizzled [m][k] bf16
    char* lb = (char*)h1s;
    int layer = blockIdx.y;
    const unsigned short* wp0 = packs + layer*4096;
    const unsigned short* wp1 = packs + 12288 + layer*16384;
    unsigned short* h2 = h2all + (size_t)layer * (Zc*Nc*Nc*NHc);

    int t   = threadIdx.x;
    int w   = t >> 6;
    int l   = t & 63;
    int g16 = l >> 4;
    int c   = l & 15;
    int p0  = blockIdx.x * 64;
    int z   = p0 >> 14;
    int a   = (p0 >> 7) & 127;
    int b0  = p0 & 127;

    int bp = b0 + 16*w + c;
    float ax = geom[(z*Nc + a)*3 + 0];
    float ay = geom[(z*Nc + a)*3 + 1];
    float az = geom[(z*Nc + a)*3 + 2];
    float dx = geom[(z*Nc + bp)*3 + 0] - ax;
    float dy = geom[(z*Nc + bp)*3 + 1] - ay;
    float dz = geom[(z*Nc + bp)*3 + 2] - az;
    float rm = sqrtf(dx*dx + dy*dy + dz*dz);

    // basis A-fragment, computed in-register (K=32 covered by one frag)
    FragU af;
    #pragma unroll
    for (int e = 0; e < 8; e++){
        int k = kmap(l, e);
        float x = fmaf(rm, 3.1f, -(float)k);   // (r - k*step)/step, step=10/31
        float v = 0.0f;
        if (fabsf(x) < 1.0f){ float cc = __cosf(1.57079632679f*x); v = cc*cc; }
        af.u[e] = (unsigned short)cvtpk_bf16(v, v);
    }

    // phase 1: y1 = basis @ w0pack (5/sqrt32 folded)
    f32x4 acc[8];
    #pragma unroll
    for (int t8 = 0; t8 < 8; t8++) acc[t8] = (f32x4){0.f,0.f,0.f,0.f};
    #pragma unroll
    for (int t8 = 0; t8 < 8; t8++){
        bf16x8 bf = *reinterpret_cast<const bf16x8*>(wp0 + ((t8*64 + l) << 3));
        acc[t8] = __builtin_amdgcn_mfma_f32_16x16x32_bf16(af.v, bf, acc[t8], 0, 0, 0);
    }
    #pragma unroll
    for (int t8 = 0; t8 < 8; t8++){
        #pragma unroll
        for (int rg = 0; rg < 4; rg++){
            int m = 16*w + 4*g16 + rg;
            int n = 16*t8 + c;
            int off = ((m << 8) + (n << 1)) ^ ((m & 7) << 4);
            *(unsigned short*)(lb + off) = (unsigned short)cvtpk_bf16(ssp5_post(acc[t8][rg]), 0.0f);
        }
    }
    __syncthreads();

    // phase 2: y2 = h1 @ w1pack (5/sqrt128 folded)
    f32x4 acc2[8];
    #pragma unroll
    for (int t8 = 0; t8 < 8; t8++) acc2[t8] = (f32x4){0.f,0.f,0.f,0.f};
    int mrow = 16*w + c;
    int sw   = (mrow & 7) << 4;
    #pragma unroll
    for (int kk = 0; kk < 4; kk++){
        int ob = (mrow << 8) + (kk << 6) + (g16 << 3);
        FragU a2;
        a2.q2[0] = *(const uint2*)(lb + (ob ^ sw));
        a2.q2[1] = *(const uint2*)(lb + ((ob + 32) ^ sw));
        #pragma unroll
        for (int t8 = 0; t8 < 8; t8++){
            bf16x8 bf = *reinterpret_cast<const bf16x8*>(wp1 + (((kk*8 + t8)*64 + l) << 3));
            acc2[t8] = __builtin_amdgcn_mfma_f32_16x16x32_bf16(a2.v, bf, acc2[t8], 0, 0, 0);
        }
    }
    size_t rowbase = ((size_t)((z*Nc + a)*Nc + b0)) * NHc;
    #pragma unroll
    for (int t8 = 0; t8 < 8; t8++){
        #pragma unroll
        for (int rg = 0; rg < 4; rg++){
            int m = 16*w + 4*g16 + rg;
            h2[rowbase + (size_t)m*NHc + 16*t8 + c] =
                (unsigned short)cvtpk_bf16(ssp5_post(acc2[t8][rg]), 0.0f);
        }
    }
}

// ---------------------------------------------------------------------------
// MFMA gemm3: partial[s][z][a][i] = sum_{bm in slice s} h2[z,a,bm]*gt[z,i,bm]
// grid = (64 k-slices, 2 a-tiles of 64, Z); 256 thr = 4 waves.
template<int DOUT>
__global__ __launch_bounds__(256) void k_gemm3m(
    const unsigned short* __restrict__ h2, const unsigned short* __restrict__ gt,
    float* __restrict__ partial)
{
    __shared__ unsigned short Ash[64*256];     // 32 KB swizzled [r][k]
    __shared__ unsigned short Bsh[DOUT*256];   // 32/16 KB swizzled [c][k]
    int t = threadIdx.x;
    int w = t >> 6, l = t & 63;
    int g16 = l >> 4, c16 = l & 15;
    int s  = blockIdx.x;        // 0..63 k-slice (256 bm each)
    int at = blockIdx.y;        // 0..1
    int z  = blockIdx.z;
    int a0 = at*64;
    int k0 = s*256;

    {
        const unsigned short* src = h2 + ((size_t)(z*Nc + a0))*(Nc*NHc) + k0;
        #pragma unroll
        for (int it = 0; it < 8; it++){
            int idx = it*256 + t;
            int r = idx >> 5, c8 = idx & 31;
            uint4 v = *reinterpret_cast<const uint4*>(src + (size_t)r*(Nc*NHc) + c8*8);
            int byte = (r*512 + c8*16) ^ ((r & 7) << 4);
            *reinterpret_cast<uint4*>((char*)Ash + byte) = v;
        }
    }
    {
        const unsigned short* src = gt + ((size_t)z*DOUT)*(Nc*NHc) + k0;
        #pragma unroll
        for (int it = 0; it < DOUT/8; it++){
            int idx = it*256 + t;
            int r = idx >> 5, c8 = idx & 31;
            uint4 v = *reinterpret_cast<const uint4*>(src + (size_t)r*(Nc*NHc) + c8*8);
            int byte = (r*512 + c8*16) ^ ((r & 7) << 4);
            *reinterpret_cast<uint4*>((char*)Bsh + byte) = v;
        }
    }
    __syncthreads();

    constexpr int NT = DOUT/16;
    f32x4 acc[NT];
    #pragma unroll
    for (int nt = 0; nt < NT; nt++) acc[nt] = (f32x4){0.f,0.f,0.f,0.f};
    char* Ab = (char*)Ash; char* Bb = (char*)Bsh;
    int ar  = 16*w + c16;
    int asw = (ar & 7) << 4;
    #pragma unroll
    for (int ks = 0; ks < 8; ks++){
        FragU afr;
        int abyte = ar*512 + ks*64 + g16*8;
        afr.q2[0] = *(const uint2*)(Ab + (abyte ^ asw));
        afr.q2[1] = *(const uint2*)(Ab + ((abyte + 32) ^ asw));
        #pragma unroll
        for (int nt = 0; nt < NT; nt++){
            int br  = nt*16 + c16;
            int bsw = (br & 7) << 4;
            int bbyte = br*512 + ks*64 + g16*8;
            FragU bfr;
            bfr.q2[0] = *(const uint2*)(Bb + (bbyte ^ bsw));
            bfr.q2[1] = *(const uint2*)(Bb + ((bbyte + 32) ^ bsw));
            acc[nt] = __builtin_amdgcn_mfma_f32_16x16x32_bf16(afr.v, bfr.v, acc[nt], 0, 0, 0);
        }
    }
    #pragma unroll
    for (int nt = 0; nt < NT; nt++){
        #pragma unroll
        for (int rg = 0; rg < 4; rg++){
            int a = a0 + 16*w + 4*g16 + rg;
            int i = nt*16 + c16;
            partial[(((size_t)s*Zc + z)*Nc + a)*DOUT + i] = acc[nt][rg];
        }
    }
}

// ---------------------------------------------------------------------------
// Fused layer-2 epilogue + x1 matmul.  grid = Z*N blocks, 128 threads.
__global__ __launch_bounds__(128) void k_x1f(
    const float* __restrict__ part, const float* __restrict__ mask,
    const float* __restrict__ geo_pn,
    const float* __restrict__ w, const float* __restrict__ b,
    float* __restrict__ x1)
{
    int zn = blockIdx.x;
    int c  = threadIdx.x;   // 128
    __shared__ float feat[Cc];
    float fv;
    if (c < MLPHc){
        float s = 0.0f;
        #pragma unroll
        for (int sl = 0; sl < SLc; sl++)
            s += part[(size_t)sl*(Zc*Nc*MLPHc) + zn*MLPHc + c];
        fv = sp5(s) * mask[zn];
    } else {
        fv = geo_pn[zn*GEOc + (c - MLPHc)];
    }
    feat[c] = fv;
    __syncthreads();
    float s = b[c];
    for (int k = 0; k < Cc; k++) s = fmaf(feat[k], w[k*Cc + c], s);
    x1[zn*Cc + c] = s;
}

// ---------------------------------------------------------------------------
// Fused BatchNorm1d(natoms) on x1 + leaky + x2 matmul.  grid = N, 256 thr.
__global__ __launch_bounds__(256) void k_bnx2(
    const float* __restrict__ x1, const float* __restrict__ g1,
    const float* __restrict__ b1, const float* __restrict__ e2w,
    const float* __restrict__ e2b, float* __restrict__ x2)
{
    int n = blockIdx.x;
    int t = threadIdx.x;
    __shared__ float xsh[Zc][Cc];
    __shared__ float ssum[4], ssq[4];
    float sum = 0.0f, sq = 0.0f;
    for (int idx = t; idx < Zc*Cc; idx += 256){
        int z = idx >> 7, c = idx & 127;
        float v = x1[((size_t)z*Nc + n)*Cc + c];
        xsh[z][c] = v;
        sum += v; sq += v*v;
    }
    #pragma unroll
    for (int off = 32; off > 0; off >>= 1){
        sum += __shfl_down(sum, off);
        sq  += __shfl_down(sq,  off);
    }
    if ((t & 63) == 0){ ssum[t >> 6] = sum; ssq[t >> 6] = sq; }
    __syncthreads();
    float tot  = ssum[0] + ssum[1] + ssum[2] + ssum[3];
    float totq = ssq[0]  + ssq[1]  + ssq[2]  + ssq[3];
    const float inv = 1.0f / (float)(Zc*Cc);
    float mu   = tot * inv;
    float var  = totq * inv - mu*mu;
    float rstd = rsqrtf(var + 1e-5f);
    float ga = g1[n], be = b1[n];
    for (int idx = t; idx < Zc*Cc; idx += 256){
        int z = idx >> 7, c = idx & 127;
        float v = (xsh[z][c] - mu) * rstd * ga + be;
        xsh[z][c] = v > 0.0f ? v : 0.2f*v;
    }
    __syncthreads();
    #pragma unroll
    for (int z = 0; z < Zc; z++){
        float s = e2b[t];
        for (int k = 0; k < Cc; k++) s = fmaf(xsh[z][k], e2w[k*2*Cc + t], s);
        x2[((size_t)z*Nc + n)*2*Cc + t] = s;
    }
}

// BatchNorm1d(natoms) + leaky in place (for x2).
template<int CC>
__global__ __launch_bounds__(256) void k_bn(
    float* __restrict__ x, const float* __restrict__ gamma,
    const float* __restrict__ beta)
{
    int n = blockIdx.x;
    int t = threadIdx.x;
    __shared__ float ssum[4], ssq[4];
    float sum = 0.0f, sq = 0.0f;
    for (int idx = t; idx < Zc*CC; idx += 256){
        int z = idx / CC, c = idx % CC;
        float v = x[((size_t)z*Nc + n)*CC + c];
        sum += v; sq += v*v;
    }
    #pragma unroll
    for (int off = 32; off > 0; off >>= 1){
        sum += __shfl_down(sum, off);
        sq  += __shfl_down(sq,  off);
    }
    if ((t & 63) == 0){ ssum[t >> 6] = sum; ssq[t >> 6] = sq; }
    __syncthreads();
    float tot  = ssum[0] + ssum[1] + ssum[2] + ssum[3];
    float totq = ssq[0]  + ssq[1]  + ssq[2]  + ssq[3];
    const float inv = 1.0f / (float)(Zc*CC);
    float mu   = tot * inv;
    float var  = totq * inv - mu*mu;
    float rstd = rsqrtf(var + 1e-5f);
    float ga = gamma[n], be = beta[n];
    for (int idx = t; idx < Zc*CC; idx += 256){
        int z = idx / CC, c = idx % CC;
        size_t o = ((size_t)z*Nc + n)*CC + c;
        float v = (x[o] - mu) * rstd * ga + be;
        x[o] = v > 0.0f ? v : 0.2f*v;
    }
}

__global__ __launch_bounds__(256) void k_out(
    const float* __restrict__ x2n, const float* __restrict__ mask,
    float* __restrict__ out)
{
    int z = blockIdx.x;
    int c = threadIdx.x;   // 256
    float s = 0.0f;
    for (int n = 0; n < Nc; n++)
        s += x2n[((size_t)z*Nc + n)*2*Cc + c] * mask[z*Nc + n];
    out[z*2*Cc + c] = s;
}

// ---------------------------------------------------------------------------
extern "C" void kernel_launch(void* const* d_in, const int* in_sizes, int n_in,
                              void* d_out, int out_size, void* d_ws, size_t ws_size,
                              hipStream_t stream)
{
    const int*   features = (const int*)  d_in[0];
    const float* geom     = (const float*)d_in[1];
    const float* mask     = (const float*)d_in[2];
    const float* emb      = (const float*)d_in[3];
    const float* rw[3][3] = {
        {(const float*)d_in[4],  (const float*)d_in[5],  (const float*)d_in[6]},
        {(const float*)d_in[7],  (const float*)d_in[8],  (const float*)d_in[9]},
        {(const float*)d_in[10], (const float*)d_in[11], (const float*)d_in[12]}};
    const float* pw0 = (const float*)d_in[13]; const float* pb0 = (const float*)d_in[14];
    const float* w1a = (const float*)d_in[15]; const float* b1a = (const float*)d_in[16];
    const float* w1b = (const float*)d_in[17]; const float* b1b = (const float*)d_in[18];
    const float* w2a = (const float*)d_in[19]; const float* b2a = (const float*)d_in[20];
    const float* w2b = (const float*)d_in[21]; const float* b2b = (const float*)d_in[22];
    const float* e1w = (const float*)d_in[23]; const float* e1b = (const float*)d_in[24];
    const float* bn1g= (const float*)d_in[25]; const float* bn1b= (const float*)d_in[26];
    const float* e2w = (const float*)d_in[27]; const float* e2b = (const float*)d_in[28];
    const float* bn2g= (const float*)d_in[29]; const float* bn2b= (const float*)d_in[30];

    // workspace layout (float units from base)
    float* ws = (float*)d_ws;
    unsigned short* h2buf = (unsigned short*)ws;               // 3*Z*N*N*NH ushort
    unsigned short* gt    = (unsigned short*)(ws + 12582912);  // Z*64*16384 ushort
    float* part   = ws + 12582912 + 2097152;                   // SL*Z*N*64 = 2097152
    float* f0     = part + 2097152;                            // Z*N*EMB   = 8192
    float* f1     = f0 + 8192;                                 // Z*N*32    = 16384
    float* f2     = f1 + 16384;                                // Z*N*32    = 16384
    float* geo_pn = f2 + 16384;                                // Z*N*64    = 32768
    float* x1     = geo_pn + 32768;                            // Z*N*C     = 65536
    float* x2     = x1 + 65536;                                // Z*N*2C    = 131072
    unsigned short* packs = (unsigned short*)(x2 + 131072);    // 61440 ushorts
    (void)ws_size; (void)in_sizes; (void)n_in; (void)out_size;

    const size_t H2L = (size_t)Zc*Nc*Nc*NHc;                   // per-layer h2 elements

    k_packw<<<dim3(80, 3), 256, 0, stream>>>(rw[0][0], rw[0][1], rw[1][0], rw[1][1],
                                             rw[2][0], rw[2][1], packs);
    k_pointnet<<<Zc*Nc, 64, 0, stream>>>(geom, mask, pw0, pb0, w1a, b1a, w1b, b1b,
                                         w2a, b2a, w2b, b2b, features, emb, geo_pn, f0);
    // all 3 layers' pair-MLPs in one launch (independent of f-chain)
    k_pairmlp<<<dim3(Zc*Nc*Nc/64, 3), 256, 0, stream>>>(geom, packs, h2buf);

    // layer 0: din=16(EMB), dout=32
    k_gmat<16,32><<<dim3(Zc*Nc/8, (NHc*32)/256), 256, 0, stream>>>(f0, rw[0][2], gt);
    k_gemm3m<32><<<dim3(SLc,2,Zc), 256, 0, stream>>>(h2buf, gt, part);
    k_epi<32><<<(Zc*Nc*32 + 255)/256, 256, 0, stream>>>(part, mask, f1);
    // layer 1: din=32, dout=32
    k_gmat<32,32><<<dim3(Zc*Nc/8, (NHc*32)/256), 256, 0, stream>>>(f1, rw[1][2], gt);
    k_gemm3m<32><<<dim3(SLc,2,Zc), 256, 0, stream>>>(h2buf + H2L, gt, part);
    k_epi<32><<<(Zc*Nc*32 + 255)/256, 256, 0, stream>>>(part, mask, f2);
    // layer 2: din=32, dout=64
    k_gmat<32,64><<<dim3(Zc*Nc/8, (NHc*64)/256), 256, 0, stream>>>(f2, rw[2][2], gt);
    k_gemm3m<64><<<dim3(SLc,2,Zc), 256, 0, stream>>>(h2buf + 2*H2L, gt, part);

    // fused epilogue2 + x1 ; fused bn1 + x2 ; bn2 ; masked sum
    k_x1f<<<Zc*Nc, 128, 0, stream>>>(part, mask, geo_pn, e1w, e1b, x1);
    k_bnx2<<<Nc, 256, 0, stream>>>(x1, bn1g, bn1b, e2w, e2b, x2);
    k_bn<2*Cc><<<Nc, 256, 0, stream>>>(x2, bn2g, bn2b);
    k_out<<<Zc, 256, 0, stream>>>(x2, mask, (float*)d_out);
}

// Round 8
// 160.232 us; speedup vs baseline: 1.0790x; 1.0790x over previous
//
#include <hip/hip_runtime.h>
#include <math.h>

// Sizes (fixed by the reference)
#define Zc   4
#define Nc   128
#define EMBc 16
#define L0c  32
#define MLPHc 64
#define GEOc 64
#define NBc  32
#define NHc  128
#define Cc   128   // MLPH + GEO
#define SLc  64    // split-K slices in gemm3

typedef float  f32x4  __attribute__((ext_vector_type(4)));
typedef short  bf16x8 __attribute__((ext_vector_type(8)));

union FragU {
    bf16x8 v;
    unsigned short u[8];
    uint2 q2[2];
};

// accurate softplus-shifted (fp32 chain)
__device__ __forceinline__ float sp5(float x){
    float y = 5.0f * x;
    float t = fabsf(y);
    return (fmaxf(y, 0.0f) + log1pf(__expf(-t))) * 0.2f;
}
// post-accumulator activation for MFMA path: input y = 5*preact (5 folded
// into packed weights).  ssp(y/5) = 0.2*(max(y,0)+log(1+exp(-|y|))) - log2/5
__device__ __forceinline__ float ssp5_post(float y){
    float e = __expf(-fabsf(y));
    float u = fmaxf(y, 0.0f) + __logf(1.0f + e);
    return fmaf(0.2f, u, -0.13862943611198906f);
}

// single-instruction f32->bf16 (RNE) via v_cvt_pk; low half = src0
__device__ __forceinline__ unsigned int cvtpk_bf16(float a, float b){
    unsigned int r;
    asm("v_cvt_pk_bf16_f32 %0, %1, %2" : "=v"(r) : "v"(a), "v"(b));
    return r;
}
__device__ __forceinline__ unsigned short f2bf(float f){   // packw only
    unsigned int u = __float_as_uint(f);
    unsigned int r = (u + 0x7FFFu + ((u >> 16) & 1u)) >> 16;
    return (unsigned short)r;
}

// shared k-map for MFMA fragments (A-gen and B-pack must agree)
__device__ __forceinline__ int kmap(int l, int e){
    return 4*((l >> 4) & 3) + (e & 3) + 16*(e >> 2);
}

// ---------------------------------------------------------------------------
// Pre-pack radial-MLP weights into per-lane MFMA B-fragment order (bf16),
// folding 5/sqrt(fan_in).  grid = (80,3), 256 thr.
__global__ __launch_bounds__(256) void k_packw(
    const float* __restrict__ w00, const float* __restrict__ w10,
    const float* __restrict__ w01, const float* __restrict__ w11,
    const float* __restrict__ w02, const float* __restrict__ w12,
    unsigned short* __restrict__ packs)
{
    int layer = blockIdx.y;
    const float* w0s = (layer == 0) ? w00 : (layer == 1) ? w01 : w02;
    const float* w1s = (layer == 0) ? w10 : (layer == 1) ? w11 : w12;
    unsigned short* p0 = packs + layer*4096;
    unsigned short* p1 = packs + 12288 + layer*16384;
    int idx = blockIdx.x*256 + threadIdx.x;
    if (idx < 4096){
        int t8 = idx >> 9, l = (idx >> 3) & 63, e = idx & 7;
        int k = kmap(l, e);
        int n = (t8 << 4) + (l & 15);
        p0[idx] = f2bf(w0s[k*NHc + n] * 0.8838834764831844f);    // 5/sqrt(32)
    } else {
        int j = idx - 4096;
        int fid = j >> 9, l = (j >> 3) & 63, e = j & 7;
        int kk = fid >> 3, t8 = fid & 7;
        int k = 32*kk + kmap(l, e);
        int n = 16*t8 + (l & 15);
        p1[j] = f2bf(w1s[k*NHc + n] * 0.4419417382415922f);      // 5/sqrt(128)
    }
}

// ---------------------------------------------------------------------------
// ResnetPointnet per atom + embedding lookup (f0 pre-scaled for gmat).
__global__ __launch_bounds__(64) void k_pointnet(
    const float* __restrict__ geom, const float* __restrict__ mask,
    const float* __restrict__ pw0, const float* __restrict__ pb0,
    const float* __restrict__ w1a, const float* __restrict__ b1a,
    const float* __restrict__ w1b, const float* __restrict__ b1b,
    const float* __restrict__ w2a, const float* __restrict__ b2a,
    const float* __restrict__ w2b, const float* __restrict__ b2b,
    const int*   __restrict__ features, const float* __restrict__ emb,
    float* __restrict__ geo_pn, float* __restrict__ f0)
{
    int zn = blockIdx.x;
    int c  = threadIdx.x;            // 0..63
    __shared__ float cur[GEOc];
    __shared__ float tmp[GEOc];
    float gx = geom[zn*3+0], gy = geom[zn*3+1], gz = geom[zn*3+2];
    float v = fmaf(gx, pw0[0*GEOc+c], fmaf(gy, pw0[1*GEOc+c], fmaf(gz, pw0[2*GEOc+c], pb0[c])));
    const float* WA[2] = {w1a, w2a}; const float* BA[2] = {b1a, b2a};
    const float* WB[2] = {w1b, w2b}; const float* BB[2] = {b1b, b2b};
    #pragma unroll
    for (int blk = 0; blk < 2; blk++){
        cur[c] = v;
        __syncthreads();
        float s = BA[blk][c];
        for (int k = 0; k < GEOc; k++) s = fmaf(fmaxf(cur[k], 0.0f), WA[blk][k*GEOc+c], s);
        tmp[c] = s;
        __syncthreads();
        float s2 = BB[blk][c];
        for (int k = 0; k < GEOc; k++) s2 = fmaf(fmaxf(tmp[k], 0.0f), WB[blk][k*GEOc+c], s2);
        v = v + s2;
        __syncthreads();
    }
    geo_pn[zn*GEOc + c] = v * mask[zn];
    if (c < EMBc){
        int fi = features[zn];
        // one mask (einsum's), Y0/128 scale pre-folded for gmat
        f0[zn*EMBc + c] = emb[fi*EMBc + c] * mask[zn] * 0.0022038655607334227f;
    }
}

// ---------------------------------------------------------------------------
// g_t[z][i][b*NH+m] = sum_j w2[m*DOUT+i, j] * f[zb,j]  (bf16, transposed)
template<int DIN, int DOUT>
__global__ __launch_bounds__(256) void k_gmat(
    const float* __restrict__ f, const float* __restrict__ w2,
    unsigned short* __restrict__ gt)
{
    __shared__ float fsh[8][DIN];
    int t   = threadIdx.x;
    int zb0 = blockIdx.x * 8;
    if (t < 8*DIN){
        int r = t / DIN, j = t % DIN;
        fsh[r][j] = f[(zb0 + r)*DIN + j];
    }
    __syncthreads();
    int mi = blockIdx.y * 256 + t;      // = i*NH + m
    int m_ = mi & (NHc-1);
    int i_ = mi >> 7;
    const float* wrow = w2 + (size_t)(m_*DOUT + i_) * DIN;
    float s[8];
    #pragma unroll
    for (int r = 0; r < 8; r++) s[r] = 0.0f;
    #pragma unroll
    for (int j4 = 0; j4 < DIN/4; j4++){
        float4 w = *reinterpret_cast<const float4*>(&wrow[j4*4]);
        #pragma unroll
        for (int q = 0; q < 4; q++){
            float wv = reinterpret_cast<const float*>(&w)[q];
            int j = j4*4 + q;
            #pragma unroll
            for (int r = 0; r < 8; r++)
                s[r] = fmaf(fsh[r][j], wv, s[r]);
        }
    }
    int z = zb0 >> 7;
    #pragma unroll
    for (int r = 0; r < 8; r++){
        int b = (zb0 + r) & (Nc-1);
        gt[((size_t)z*DOUT + i_)*(Nc*NHc) + b*NHc + m_] = (unsigned short)cvtpk_bf16(s[r], s[r]);
    }
}

// Fused previous-layer epilogue + gmat (part re-reads are L2-hot, 4 MB).
template<int DIN, int DOUT>
__global__ __launch_bounds__(256) void k_egmat(
    const float* __restrict__ part, const float* __restrict__ mask,
    const float* __restrict__ w2, unsigned short* __restrict__ gt)
{
    __shared__ float fsh[8][DIN];
    int t   = threadIdx.x;
    int zb0 = blockIdx.x * 8;
    for (int idx = t; idx < 8*DIN; idx += 256){
        int r = idx / DIN, j = idx % DIN;
        int zb = zb0 + r;
        float s = 0.0f;
        #pragma unroll
        for (int sl = 0; sl < SLc; sl++)
            s += part[(size_t)sl*(Zc*Nc*DIN) + zb*DIN + j];
        float m = mask[zb];
        // f*mask (post-act) then *mask (einsum) -> m*m; Y0/128 folded
        fsh[r][j] = sp5(s) * m * m * 0.0022038655607334227f;
    }
    __syncthreads();
    int mi = blockIdx.y * 256 + t;
    int m_ = mi & (NHc-1);
    int i_ = mi >> 7;
    const float* wrow = w2 + (size_t)(m_*DOUT + i_) * DIN;
    float s[8];
    #pragma unroll
    for (int r = 0; r < 8; r++) s[r] = 0.0f;
    #pragma unroll
    for (int j4 = 0; j4 < DIN/4; j4++){
        float4 w = *reinterpret_cast<const float4*>(&wrow[j4*4]);
        #pragma unroll
        for (int q = 0; q < 4; q++){
            float wv = reinterpret_cast<const float*>(&w)[q];
            int j = j4*4 + q;
            #pragma unroll
            for (int r = 0; r < 8; r++)
                s[r] = fmaf(fsh[r][j], wv, s[r]);
        }
    }
    int z = zb0 >> 7;
    #pragma unroll
    for (int r = 0; r < 8; r++){
        int b = (zb0 + r) & (Nc-1);
        gt[((size_t)z*DOUT + i_)*(Nc*NHc) + b*NHc + m_] = (unsigned short)cvtpk_bf16(s[r], s[r]);
    }
}

// ---------------------------------------------------------------------------
// MFMA pair-MLP, all 3 layers, SYMMETRY-halved: h2(a,b)=h2(b,a) since it
// depends only on r_ab.  Waves whose whole 16-pair range is below the
// diagonal exit early; computed pairs with b>a mirror-write h2[b][a].
// Waves are LDS-independent (own 16 rows) -> no barrier needed.
__global__ __launch_bounds__(256, 2) void k_pairmlp(
    const float* __restrict__ geom,
    const unsigned short* __restrict__ packs,
    unsigned short* __restrict__ h2all)
{
    __shared__ unsigned short h1s[64*128];   // 16 KB, XOR-swizzled [m][k] bf16
    char* lb = (char*)h1s;
    int t   = threadIdx.x;
    int w   = t >> 6;
    int l   = t & 63;
    int g16 = l >> 4;
    int c   = l & 15;
    int p0  = blockIdx.x * 64;
    int z   = p0 >> 14;
    int a   = (p0 >> 7) & 127;
    int b0  = p0 & 127;

    // symmetric skip: pairs b in [b0+16w, b0+16w+16); if all b < a the
    // mirror writes from blocks (b,.) cover h2[a][b].
    if (b0 + 16*w + 15 < a) return;

    int layer = blockIdx.y;
    const unsigned short* wp0 = packs + layer*4096;
    const unsigned short* wp1 = packs + 12288 + layer*16384;
    unsigned short* h2 = h2all + (size_t)layer * (Zc*Nc*Nc*NHc);

    int bp = b0 + 16*w + c;
    float ax = geom[(z*Nc + a)*3 + 0];
    float ay = geom[(z*Nc + a)*3 + 1];
    float az = geom[(z*Nc + a)*3 + 2];
    float dx = geom[(z*Nc + bp)*3 + 0] - ax;
    float dy = geom[(z*Nc + bp)*3 + 1] - ay;
    float dz = geom[(z*Nc + bp)*3 + 2] - az;
    float rm = sqrtf(dx*dx + dy*dy + dz*dz);

    // basis A-fragment, computed in-register (K=32 covered by one frag)
    FragU af;
    #pragma unroll
    for (int e = 0; e < 8; e++){
        int k = kmap(l, e);
        float x = fmaf(rm, 3.1f, -(float)k);   // (r - k*step)/step, step=10/31
        float v = 0.0f;
        if (fabsf(x) < 1.0f){ float cc = __cosf(1.57079632679f*x); v = cc*cc; }
        af.u[e] = (unsigned short)cvtpk_bf16(v, v);
    }

    // phase 1: y1 = basis @ w0pack (5/sqrt32 folded)
    f32x4 acc[8];
    #pragma unroll
    for (int t8 = 0; t8 < 8; t8++) acc[t8] = (f32x4){0.f,0.f,0.f,0.f};
    #pragma unroll
    for (int t8 = 0; t8 < 8; t8++){
        bf16x8 bf = *reinterpret_cast<const bf16x8*>(wp0 + ((t8*64 + l) << 3));
        acc[t8] = __builtin_amdgcn_mfma_f32_16x16x32_bf16(af.v, bf, acc[t8], 0, 0, 0);
    }
    #pragma unroll
    for (int t8 = 0; t8 < 8; t8++){
        #pragma unroll
        for (int rg = 0; rg < 4; rg++){
            int m = 16*w + 4*g16 + rg;
            int n = 16*t8 + c;
            int off = ((m << 8) + (n << 1)) ^ ((m & 7) << 4);
            *(unsigned short*)(lb + off) = (unsigned short)cvtpk_bf16(ssp5_post(acc[t8][rg]), 0.0f);
        }
    }
    // no __syncthreads: wave w wrote rows [16w,16w+16) and reads only those.

    // phase 2: y2 = h1 @ w1pack (5/sqrt128 folded)
    f32x4 acc2[8];
    #pragma unroll
    for (int t8 = 0; t8 < 8; t8++) acc2[t8] = (f32x4){0.f,0.f,0.f,0.f};
    int mrow = 16*w + c;
    int sw   = (mrow & 7) << 4;
    #pragma unroll
    for (int kk = 0; kk < 4; kk++){
        int ob = (mrow << 8) + (kk << 6) + (g16 << 3);
        FragU a2;
        a2.q2[0] = *(const uint2*)(lb + (ob ^ sw));
        a2.q2[1] = *(const uint2*)(lb + ((ob + 32) ^ sw));
        #pragma unroll
        for (int t8 = 0; t8 < 8; t8++){
            bf16x8 bf = *reinterpret_cast<const bf16x8*>(wp1 + (((kk*8 + t8)*64 + l) << 3));
            acc2[t8] = __builtin_amdgcn_mfma_f32_16x16x32_bf16(a2.v, bf, acc2[t8], 0, 0, 0);
        }
    }
    size_t zbase = (size_t)z*Nc*Nc*NHc;
    #pragma unroll
    for (int t8 = 0; t8 < 8; t8++){
        #pragma unroll
        for (int rg = 0; rg < 4; rg++){
            int m = 16*w + 4*g16 + rg;
            int b = b0 + m;
            unsigned short val = (unsigned short)cvtpk_bf16(ssp5_post(acc2[t8][rg]), 0.0f);
            h2[zbase + ((size_t)a*Nc + b)*NHc + 16*t8 + c] = val;
            if (b > a)
                h2[zbase + ((size_t)b*Nc + a)*NHc + 16*t8 + c] = val;
        }
    }
}

// ---------------------------------------------------------------------------
// MFMA gemm3: partial[s][z][a][i] = sum_{bm in slice s} h2[z,a,bm]*gt[z,i,bm]
// grid = (64 k-slices, 2 a-tiles of 64, Z); 256 thr = 4 waves.
template<int DOUT>
__global__ __launch_bounds__(256) void k_gemm3m(
    const unsigned short* __restrict__ h2, const unsigned short* __restrict__ gt,
    float* __restrict__ partial)
{
    __shared__ unsigned short Ash[64*256];     // 32 KB swizzled [r][k]
    __shared__ unsigned short Bsh[DOUT*256];   // 32/16 KB swizzled [c][k]
    int t = threadIdx.x;
    int w = t >> 6, l = t & 63;
    int g16 = l >> 4, c16 = l & 15;
    int s  = blockIdx.x;        // 0..63 k-slice (256 bm each)
    int at = blockIdx.y;        // 0..1
    int z  = blockIdx.z;
    int a0 = at*64;
    int k0 = s*256;

    {
        const unsigned short* src = h2 + ((size_t)(z*Nc + a0))*(Nc*NHc) + k0;
        #pragma unroll
        for (int it = 0; it < 8; it++){
            int idx = it*256 + t;
            int r = idx >> 5, c8 = idx & 31;
            uint4 v = *reinterpret_cast<const uint4*>(src + (size_t)r*(Nc*NHc) + c8*8);
            int byte = (r*512 + c8*16) ^ ((r & 7) << 4);
            *reinterpret_cast<uint4*>((char*)Ash + byte) = v;
        }
    }
    {
        const unsigned short* src = gt + ((size_t)z*DOUT)*(Nc*NHc) + k0;
        #pragma unroll
        for (int it = 0; it < DOUT/8; it++){
            int idx = it*256 + t;
            int r = idx >> 5, c8 = idx & 31;
            uint4 v = *reinterpret_cast<const uint4*>(src + (size_t)r*(Nc*NHc) + c8*8);
            int byte = (r*512 + c8*16) ^ ((r & 7) << 4);
            *reinterpret_cast<uint4*>((char*)Bsh + byte) = v;
        }
    }
    __syncthreads();

    constexpr int NT = DOUT/16;
    f32x4 acc[NT];
    #pragma unroll
    for (int nt = 0; nt < NT; nt++) acc[nt] = (f32x4){0.f,0.f,0.f,0.f};
    char* Ab = (char*)Ash; char* Bb = (char*)Bsh;
    int ar  = 16*w + c16;
    int asw = (ar & 7) << 4;
    #pragma unroll
    for (int ks = 0; ks < 8; ks++){
        FragU afr;
        int abyte = ar*512 + ks*64 + g16*8;
        afr.q2[0] = *(const uint2*)(Ab + (abyte ^ asw));
        afr.q2[1] = *(const uint2*)(Ab + ((abyte + 32) ^ asw));
        #pragma unroll
        for (int nt = 0; nt < NT; nt++){
            int br  = nt*16 + c16;
            int bsw = (br & 7) << 4;
            int bbyte = br*512 + ks*64 + g16*8;
            FragU bfr;
            bfr.q2[0] = *(const uint2*)(Bb + (bbyte ^ bsw));
            bfr.q2[1] = *(const uint2*)(Bb + ((bbyte + 32) ^ bsw));
            acc[nt] = __builtin_amdgcn_mfma_f32_16x16x32_bf16(afr.v, bfr.v, acc[nt], 0, 0, 0);
        }
    }
    #pragma unroll
    for (int nt = 0; nt < NT; nt++){
        #pragma unroll
        for (int rg = 0; rg < 4; rg++){
            int a = a0 + 16*w + 4*g16 + rg;
            int i = nt*16 + c16;
            partial[(((size_t)s*Zc + z)*Nc + a)*DOUT + i] = acc[nt][rg];
        }
    }
}

// ---------------------------------------------------------------------------
// Fused tail: layer-2 epilogue -> x1 -> bn1+leaky -> x2 -> bn2+leaky.
// grid = N blocks (one per atom slot), 256 threads.
__global__ __launch_bounds__(256) void k_tail(
    const float* __restrict__ part, const float* __restrict__ mask,
    const float* __restrict__ geo_pn,
    const float* __restrict__ e1w, const float* __restrict__ e1b,
    const float* __restrict__ g1, const float* __restrict__ b1,
    const float* __restrict__ e2w, const float* __restrict__ e2b,
    const float* __restrict__ g2, const float* __restrict__ b2,
    float* __restrict__ x2out)
{
    int n = blockIdx.x;
    int t = threadIdx.x;
    __shared__ float feat[Zc][Cc];     // 2 KB
    __shared__ float xln[Zc][Cc];      // 2 KB
    __shared__ float r1[4], r2[4];

    // stage A: feat[z][0:64] = sp5(sum_sl part)*mask ; feat[z][64:128] = geo_pn
    {
        int z = t >> 6, i = t & 63;
        float s = 0.0f;
        #pragma unroll
        for (int sl = 0; sl < SLc; sl++)
            s += part[((size_t)sl*Zc*Nc + z*Nc + n)*MLPHc + i];
        float m = mask[z*Nc + n];
        feat[z][i] = sp5(s) * m;
        feat[z][MLPHc + i] = geo_pn[(z*Nc + n)*GEOc + i];
    }
    __syncthreads();

    // stage B: x1 = feat @ e1w + e1b  (4z x 128c; 2 outputs/thread)
    int c  = t & 127;
    int zh = t >> 7;
    float x1v[2];
    float sum = 0.0f, sq = 0.0f;
    #pragma unroll
    for (int q = 0; q < 2; q++){
        int z = zh*2 + q;
        float s = e1b[c];
        for (int k = 0; k < Cc; k++) s = fmaf(feat[z][k], e1w[k*Cc + c], s);
        x1v[q] = s; sum += s; sq = fmaf(s, s, sq);
    }
    #pragma unroll
    for (int off = 32; off > 0; off >>= 1){
        sum += __shfl_down(sum, off);
        sq  += __shfl_down(sq,  off);
    }
    if ((t & 63) == 0){ r1[t >> 6] = sum; r2[t >> 6] = sq; }
    __syncthreads();
    {
        float tot  = r1[0]+r1[1]+r1[2]+r1[3];
        float totq = r2[0]+r2[1]+r2[2]+r2[3];
        float mu   = tot * (1.0f/512.0f);
        float var  = totq * (1.0f/512.0f) - mu*mu;
        float rstd = rsqrtf(var + 1e-5f);
        float ga = g1[n], be = b1[n];
        #pragma unroll
        for (int q = 0; q < 2; q++){
            float v = (x1v[q] - mu) * rstd * ga + be;
            xln[zh*2 + q][c] = v > 0.0f ? v : 0.2f*v;
        }
    }
    __syncthreads();

    // stage C: x2 = xln @ e2w + e2b  (4z x 256c2; 4 outputs/thread)
    float x2v[4];
    sum = 0.0f; sq = 0.0f;
    #pragma unroll
    for (int z = 0; z < Zc; z++){
        float s = e2b[t];
        for (int k = 0; k < Cc; k++) s = fmaf(xln[z][k], e2w[k*2*Cc + t], s);
        x2v[z] = s; sum += s; sq = fmaf(s, s, sq);
    }
    #pragma unroll
    for (int off = 32; off > 0; off >>= 1){
        sum += __shfl_down(sum, off);
        sq  += __shfl_down(sq,  off);
    }
    if ((t & 63) == 0){ r1[t >> 6] = sum; r2[t >> 6] = sq; }
    __syncthreads();
    {
        float tot  = r1[0]+r1[1]+r1[2]+r1[3];
        float totq = r2[0]+r2[1]+r2[2]+r2[3];
        float mu   = tot * (1.0f/1024.0f);
        float var  = totq * (1.0f/1024.0f) - mu*mu;
        float rstd = rsqrtf(var + 1e-5f);
        float ga = g2[n], be = b2[n];
        #pragma unroll
        for (int z = 0; z < Zc; z++){
            float v = (x2v[z] - mu) * rstd * ga + be;
            v = v > 0.0f ? v : 0.2f*v;
            x2out[((size_t)z*Nc + n)*2*Cc + t] = v;
        }
    }
}

__global__ __launch_bounds__(256) void k_out(
    const float* __restrict__ x2n, const float* __restrict__ mask,
    float* __restrict__ out)
{
    int z = blockIdx.x;
    int c = threadIdx.x;   // 256
    float s = 0.0f;
    for (int n = 0; n < Nc; n++)
        s += x2n[((size_t)z*Nc + n)*2*Cc + c] * mask[z*Nc + n];
    out[z*2*Cc + c] = s;
}

// ---------------------------------------------------------------------------
extern "C" void kernel_launch(void* const* d_in, const int* in_sizes, int n_in,
                              void* d_out, int out_size, void* d_ws, size_t ws_size,
                              hipStream_t stream)
{
    const int*   features = (const int*)  d_in[0];
    const float* geom     = (const float*)d_in[1];
    const float* mask     = (const float*)d_in[2];
    const float* emb      = (const float*)d_in[3];
    const float* rw[3][3] = {
        {(const float*)d_in[4],  (const float*)d_in[5],  (const float*)d_in[6]},
        {(const float*)d_in[7],  (const float*)d_in[8],  (const float*)d_in[9]},
        {(const float*)d_in[10], (const float*)d_in[11], (const float*)d_in[12]}};
    const float* pw0 = (const float*)d_in[13]; const float* pb0 = (const float*)d_in[14];
    const float* w1a = (const float*)d_in[15]; const float* b1a = (const float*)d_in[16];
    const float* w1b = (const float*)d_in[17]; const float* b1b = (const float*)d_in[18];
    const float* w2a = (const float*)d_in[19]; const float* b2a = (const float*)d_in[20];
    const float* w2b = (const float*)d_in[21]; const float* b2b = (const float*)d_in[22];
    const float* e1w = (const float*)d_in[23]; const float* e1b = (const float*)d_in[24];
    const float* bn1g= (const float*)d_in[25]; const float* bn1b= (const float*)d_in[26];
    const float* e2w = (const float*)d_in[27]; const float* e2b = (const float*)d_in[28];
    const float* bn2g= (const float*)d_in[29]; const float* bn2b= (const float*)d_in[30];

    // workspace layout (float units from base)
    float* ws = (float*)d_ws;
    unsigned short* h2buf = (unsigned short*)ws;               // 3*Z*N*N*NH ushort
    unsigned short* gt    = (unsigned short*)(ws + 12582912);  // Z*64*16384 ushort
    float* part   = ws + 12582912 + 2097152;                   // SL*Z*N*64 = 2097152
    float* f0     = part + 2097152;                            // Z*N*EMB   = 8192
    float* geo_pn = f0 + 8192;                                 // Z*N*64    = 32768
    float* x2     = geo_pn + 32768;                            // Z*N*2C    = 131072
    unsigned short* packs = (unsigned short*)(x2 + 131072);    // 61440 ushorts
    (void)ws_size; (void)in_sizes; (void)n_in; (void)out_size;

    const size_t H2L = (size_t)Zc*Nc*Nc*NHc;                   // per-layer h2 elements

    k_packw<<<dim3(80, 3), 256, 0, stream>>>(rw[0][0], rw[0][1], rw[1][0], rw[1][1],
                                             rw[2][0], rw[2][1], packs);
    k_pointnet<<<Zc*Nc, 64, 0, stream>>>(geom, mask, pw0, pb0, w1a, b1a, w1b, b1b,
                                         w2a, b2a, w2b, b2b, features, emb, geo_pn, f0);
    // all 3 layers' pair-MLPs in one launch (symmetry-halved)
    k_pairmlp<<<dim3(Zc*Nc*Nc/64, 3), 256, 0, stream>>>(geom, packs, h2buf);

    // layer 0: din=16(EMB), dout=32
    k_gmat<16,32><<<dim3(Zc*Nc/8, (NHc*32)/256), 256, 0, stream>>>(f0, rw[0][2], gt);
    k_gemm3m<32><<<dim3(SLc,2,Zc), 256, 0, stream>>>(h2buf, gt, part);
    // layer 1: din=32, dout=32  (epilogue fused into gmat; part is L2-hot)
    k_egmat<32,32><<<dim3(Zc*Nc/8, (NHc*32)/256), 256, 0, stream>>>(part, mask, rw[1][2], gt);
    k_gemm3m<32><<<dim3(SLc,2,Zc), 256, 0, stream>>>(h2buf + H2L, gt, part);
    // layer 2: din=32, dout=64
    k_egmat<32,64><<<dim3(Zc*Nc/8, (NHc*64)/256), 256, 0, stream>>>(part, mask, rw[2][2], gt);
    k_gemm3m<64><<<dim3(SLc,2,Zc), 256, 0, stream>>>(h2buf + 2*H2L, gt, part);

    // fused tail (epilogue2+x1+bn1+x2+bn2) ; masked sum
    k_tail<<<Nc, 256, 0, stream>>>(part, mask, geo_pn, e1w, e1b, bn1g, bn1b,
                                   e2w, e2b, bn2g, bn2b, x2);
    k_out<<<Zc, 256, 0, stream>>>(x2, mask, (float*)d_out);
}